// Round 4
// baseline (180.664 us; speedup 1.0000x reference)
//
#include <hip/hip_runtime.h>
#include <hip/hip_bf16.h>

// WaveletBlock fused kernel (f32 in/out): DWT -> GEMM1(+bias,SiLU) -> GEMM2(+bias) -> IDWT
// R4: 128-thread blocks (2 waves), 32-pixel half-row tiles, grid 2048.
//   LDS 16.9 KB -> ~9 blocks/CU (18 waves) for phase staggering across blocks.
//   GEMM uses 32x32x16 MFMA (4 m-tiles/wave, 1 n-tile). Phase 1 issues all 32
//   x-loads up-front (max MLP). Weights pre-converted to bf16 in d_ws.

typedef __bf16 bf16x8  __attribute__((ext_vector_type(8)));
typedef float  f32x16  __attribute__((ext_vector_type(16)));

#define SP 264  // LDS row stride in bf16 elems: 528 B = 33*16 -> rows 16B-aligned,
                // row stride == 4 mod 32 banks (<=2-way on wave-row access).

__device__ __forceinline__ unsigned short f2bf(float f) {
  __hip_bfloat16 h = __float2bfloat16(f);
  return __builtin_bit_cast(unsigned short, h);
}
__device__ __forceinline__ float bf2f(unsigned short s) {
  union { unsigned int i; float f; } v; v.i = ((unsigned int)s) << 16; return v.f;
}
__device__ __forceinline__ float silu(float f) {
  return f / (1.0f + __expf(-f));
}
__device__ __forceinline__ bf16x8 ldw8(const float* __restrict__ p) {  // f32 fallback
  const float4 a = *(const float4*)p;
  const float4 b = *(const float4*)(p + 4);
  bf16x8 r;
  r[0] = (__bf16)a.x; r[1] = (__bf16)a.y; r[2] = (__bf16)a.z; r[3] = (__bf16)a.w;
  r[4] = (__bf16)b.x; r[5] = (__bf16)b.y; r[6] = (__bf16)b.z; r[7] = (__bf16)b.w;
  return r;
}

// Prelude: f32 -> bf16 weight conversion into workspace.
__global__ __launch_bounds__(256) void cvt_w(const float* __restrict__ w1,
                                             const float* __restrict__ w2,
                                             unsigned short* __restrict__ o) {
  const int i = (blockIdx.x * 256 + threadIdx.x) * 4;  // grid 64 x 256 covers 65536
  const float4 a = *(const float4*)(w1 + i);
  const float4 b = *(const float4*)(w2 + i);
  *(ushort4*)(o + i)         = make_ushort4(f2bf(a.x), f2bf(a.y), f2bf(a.z), f2bf(a.w));
  *(ushort4*)(o + 65536 + i) = make_ushort4(f2bf(b.x), f2bf(b.y), f2bf(b.z), f2bf(b.w));
}

template <bool WBF16>
__global__ __launch_bounds__(128, 4)
void wavelet_fused(const float* __restrict__ x,
                   const void* __restrict__ w1p,
                   const float* __restrict__ b1,
                   const void* __restrict__ w2p,
                   const float* __restrict__ b2,
                   float* __restrict__ out)
{
  // One buffer, three lives: x_dwt [pix][c4] -> feat [pix][o] -> y [pix][c4].
  __shared__ unsigned short lds[32 * SP];  // 16,896 B -> ~9 blocks/CU

  const int t    = threadIdx.x;
  const int bid  = blockIdx.x;
  const int n    = bid >> 7;          // image (b*8+l); 128 blocks per image
  const int hh   = (bid >> 1) & 63;   // DWT row
  const int half = bid & 1;           // which 32-pixel half of the row

  const int ww  = t & 31;             // local pixel (phases 1/4)
  const int cg  = t >> 5;             // channel group 0..3 (16 input ch each)
  const int col = half * 32 + ww;     // global DWT column

  // ---------------- Phase 1: Haar DWT -> lds[ww][q*64+c] ----------------
  {
    // Issue ALL loads first (32 float2 in flight), then compute.
    float2 r0v[16], r1v[16];
    #pragma unroll
    for (int j = 0; j < 4; ++j)
      #pragma unroll
      for (int ci = 0; ci < 4; ++ci) {
        const int c = (cg + 4 * j) * 4 + ci;
        const float* p = x + ((size_t)(n * 64 + c) * 128 + (size_t)(2 * hh)) * 128 + 2 * col;
        r0v[j * 4 + ci] = *(const float2*)p;          // even row: (2hh,   2col/2col+1)
        r1v[j * 4 + ci] = *(const float2*)(p + 128);  // odd  row: (2hh+1, ...)
      }
    #pragma unroll
    for (int j = 0; j < 4; ++j) {
      const int c0 = (cg + 4 * j) * 4;
      float qv[4][4];
      #pragma unroll
      for (int ci = 0; ci < 4; ++ci) {
        const float x1 = r0v[j * 4 + ci].x, x3 = r0v[j * 4 + ci].y;
        const float x2 = r1v[j * 4 + ci].x, x4 = r1v[j * 4 + ci].y;
        qv[0][ci] = 0.5f * ((x1 + x2) + (x3 + x4));
        qv[1][ci] = 0.5f * ((x3 + x4) - (x1 + x2));
        qv[2][ci] = 0.5f * ((x2 + x4) - (x1 + x3));
        qv[3][ci] = 0.5f * ((x1 + x4) - (x2 + x3));
      }
      #pragma unroll
      for (int q = 0; q < 4; ++q) {
        ushort4 v = make_ushort4(f2bf(qv[q][0]), f2bf(qv[q][1]), f2bf(qv[q][2]), f2bf(qv[q][3]));
        *(ushort4*)(&lds[ww * SP + q * 64 + c0]) = v;
      }
    }
  }
  __syncthreads();

  const int wv    = t >> 6;        // wave id: o-halves of 128 rows
  const int lane  = t & 63;
  const int m     = lane & 31;     // A row-in-tile / B,C col (pixel)
  const int khalf = lane >> 5;     // k-offset half (inputs) / +4 row offset (output)

  // ---------------- Phase 2: GEMM1  D[o][pix] = conv_w . x_dwt; silu -> lds[pix][o] ----------------
  {
    f32x16 acc[4];
    #pragma unroll
    for (int mt = 0; mt < 4; ++mt)
      acc[mt] = (f32x16)(0.0f);

    #pragma unroll
    for (int k0 = 0; k0 < 256; k0 += 16) {
      bf16x8 a[4], b;
      #pragma unroll
      for (int mt = 0; mt < 4; ++mt) {  // A: conv_w rows o (L2-resident)
        const int row = wv * 128 + mt * 32 + m;
        if constexpr (WBF16)
          a[mt] = *(const bf16x8*)((const unsigned short*)w1p + row * 256 + k0 + khalf * 8);
        else
          a[mt] = ldw8((const float*)w1p + row * 256 + k0 + khalf * 8);
      }
      b = *(const bf16x8*)(&lds[m * SP + k0 + khalf * 8]);  // B: x_dwt[pix=m][k]
      #pragma unroll
      for (int mt = 0; mt < 4; ++mt)
        acc[mt] = __builtin_amdgcn_mfma_f32_32x32x16_bf16(a[mt], b, acc[mt], 0, 0, 0);
    }
    __syncthreads();  // all GEMM1 reads of lds done

    // C layout (32x32): col=lane&31(=pixel), row = (reg&3) + 8*(reg>>2) + 4*khalf
    #pragma unroll
    for (int mt = 0; mt < 4; ++mt) {
      #pragma unroll
      for (int g = 0; g < 4; ++g) {
        const int o = wv * 128 + mt * 32 + g * 8 + khalf * 4;
        const float4 bb = *(const float4*)(b1 + o);
        ushort4 v;
        v.x = f2bf(silu(acc[mt][g * 4 + 0] + bb.x));
        v.y = f2bf(silu(acc[mt][g * 4 + 1] + bb.y));
        v.z = f2bf(silu(acc[mt][g * 4 + 2] + bb.z));
        v.w = f2bf(silu(acc[mt][g * 4 + 3] + bb.w));
        *(ushort4*)(&lds[m * SP + o]) = v;
      }
    }
  }
  __syncthreads();

  // ---------------- Phase 3: GEMM2  D[c4][pix] = conv_out_w . feat -> lds[pix][c4] ----------------
  {
    f32x16 acc[4];
    #pragma unroll
    for (int mt = 0; mt < 4; ++mt)
      acc[mt] = (f32x16)(0.0f);

    #pragma unroll
    for (int k0 = 0; k0 < 256; k0 += 16) {
      bf16x8 a[4], b;
      #pragma unroll
      for (int mt = 0; mt < 4; ++mt) {
        const int row = wv * 128 + mt * 32 + m;
        if constexpr (WBF16)
          a[mt] = *(const bf16x8*)((const unsigned short*)w2p + row * 256 + k0 + khalf * 8);
        else
          a[mt] = ldw8((const float*)w2p + row * 256 + k0 + khalf * 8);
      }
      b = *(const bf16x8*)(&lds[m * SP + k0 + khalf * 8]);  // B: feat[pix=m][k]
      #pragma unroll
      for (int mt = 0; mt < 4; ++mt)
        acc[mt] = __builtin_amdgcn_mfma_f32_32x32x16_bf16(a[mt], b, acc[mt], 0, 0, 0);
    }
    __syncthreads();  // all GEMM2 reads of lds done

    #pragma unroll
    for (int mt = 0; mt < 4; ++mt) {
      #pragma unroll
      for (int g = 0; g < 4; ++g) {
        const int cb = wv * 128 + mt * 32 + g * 8 + khalf * 4;
        const float4 bb = *(const float4*)(b2 + cb);
        ushort4 v;
        v.x = f2bf(acc[mt][g * 4 + 0] + bb.x);
        v.y = f2bf(acc[mt][g * 4 + 1] + bb.y);
        v.z = f2bf(acc[mt][g * 4 + 2] + bb.z);
        v.w = f2bf(acc[mt][g * 4 + 3] + bb.w);
        *(ushort4*)(&lds[m * SP + cb]) = v;
      }
    }
  }
  __syncthreads();

  // ---------------- Phase 4: IDWT + coalesced float2 stores ----------------
  {
    float* ob_ = out + ((size_t)n * 64 * 128 + (size_t)(2 * hh)) * 128 + 2 * col;
    #pragma unroll
    for (int j = 0; j < 4; ++j) {
      const int c0 = (cg + 4 * j) * 4;
      unsigned short yb[4][4];
      #pragma unroll
      for (int q = 0; q < 4; ++q) {
        const ushort4 v = *(const ushort4*)(&lds[ww * SP + q * 64 + c0]);
        yb[q][0] = v.x; yb[q][1] = v.y; yb[q][2] = v.z; yb[q][3] = v.w;
      }
      #pragma unroll
      for (int ci = 0; ci < 4; ++ci) {
        const float y1 = 0.5f * bf2f(yb[0][ci]);
        const float y2 = 0.5f * bf2f(yb[1][ci]);
        const float y3 = 0.5f * bf2f(yb[2][ci]);
        const float y4 = 0.5f * bf2f(yb[3][ci]);
        const float s14 = y1 + y4, s23 = y2 + y3;
        const float d14 = y1 - y4, d23 = y2 - y3;
        const float oa  = s14 - s23;  // (2hh,   2col)
        const float oc  = d14 + d23;  // (2hh,   2col+1)
        const float obv = d14 - d23;  // (2hh+1, 2col)
        const float od  = s14 + s23;  // (2hh+1, 2col+1)
        float* prow = ob_ + (size_t)(c0 + ci) * (128 * 128);
        *(float2*)prow         = make_float2(oa, oc);
        *(float2*)(prow + 128) = make_float2(obv, od);
      }
    }
  }
}

extern "C" void kernel_launch(void* const* d_in, const int* in_sizes, int n_in,
                              void* d_out, int out_size, void* d_ws, size_t ws_size,
                              hipStream_t stream) {
  (void)in_sizes; (void)n_in; (void)out_size;
  const float* x  = (const float*)d_in[0];
  const float* w1 = (const float*)d_in[1];
  const float* b1 = (const float*)d_in[2];
  const float* w2 = (const float*)d_in[3];
  const float* b2 = (const float*)d_in[4];
  float* o = (float*)d_out;

  if (ws_size >= 2u * 65536u * sizeof(unsigned short)) {
    unsigned short* wb = (unsigned short*)d_ws;
    cvt_w<<<dim3(64), dim3(256), 0, stream>>>(w1, w2, wb);
    wavelet_fused<true><<<dim3(16 * 64 * 2), dim3(128), 0, stream>>>(
        x, wb, b1, wb + 65536, b2, o);
  } else {
    wavelet_fused<false><<<dim3(16 * 64 * 2), dim3(128), 0, stream>>>(
        x, w1, b1, w2, b2, o);
  }
}

// Round 5
// 165.856 us; speedup vs baseline: 1.0893x; 1.0893x over previous
//
#include <hip/hip_runtime.h>
#include <hip/hip_bf16.h>

// WaveletBlock fused kernel (f32 in/out): DWT -> GEMM1(+bias,SiLU) -> GEMM2(+bias) -> IDWT
// R5 = R3 shape (256 thr, 64-pixel row tile, 16x16x32 MFMA, grid 1024) + latency attack:
//   * register double-buffer of A (weight) fragments in both K-loops,
//     with cross-phase prefetch (GEMM1 tail prefetches GEMM2's first A frags;
//     GEMM1's first A frags issue before barrier 1 and drain under the DWT)
//   * phase-1 issues all 32 x-loads before any arithmetic (single vmcnt drain)
//   * XOR-swizzled LDS tile (exact 32 KB, no padding): unit16 ^= pix&31

typedef __bf16 bf16x8 __attribute__((ext_vector_type(8)));
typedef float  f32x4  __attribute__((ext_vector_type(4)));

__device__ __forceinline__ unsigned short f2bf(float f) {
  __hip_bfloat16 h = __float2bfloat16(f);
  return __builtin_bit_cast(unsigned short, h);
}
__device__ __forceinline__ float bf2f(unsigned short s) {
  union { unsigned int i; float f; } v; v.i = ((unsigned int)s) << 16; return v.f;
}
__device__ __forceinline__ float silu(float f) {
  return f / (1.0f + __expf(-f));
}
// Swizzled flat index into the 64x256 bf16 tile: 16B unit XOR'd with pix&31.
// All accesses use k%8 in {0,4} with 4-element groups, or full 8-element groups.
__device__ __forceinline__ int sw(int pix, int k) {
  return pix * 256 + ((((k >> 3) ^ pix) & 31) << 3) + (k & 7);
}
__device__ __forceinline__ bf16x8 ldw8(const float* __restrict__ p) {  // f32 fallback
  const float4 a = *(const float4*)p;
  const float4 b = *(const float4*)(p + 4);
  bf16x8 r;
  r[0] = (__bf16)a.x; r[1] = (__bf16)a.y; r[2] = (__bf16)a.z; r[3] = (__bf16)a.w;
  r[4] = (__bf16)b.x; r[5] = (__bf16)b.y; r[6] = (__bf16)b.z; r[7] = (__bf16)b.w;
  return r;
}

// Prelude: f32 -> bf16 weight conversion into workspace.
__global__ __launch_bounds__(256) void cvt_w(const float* __restrict__ w1,
                                             const float* __restrict__ w2,
                                             unsigned short* __restrict__ o) {
  const int i = (blockIdx.x * 256 + threadIdx.x) * 4;  // grid 64 x 256 covers 65536
  const float4 a = *(const float4*)(w1 + i);
  const float4 b = *(const float4*)(w2 + i);
  *(ushort4*)(o + i)         = make_ushort4(f2bf(a.x), f2bf(a.y), f2bf(a.z), f2bf(a.w));
  *(ushort4*)(o + 65536 + i) = make_ushort4(f2bf(b.x), f2bf(b.y), f2bf(b.z), f2bf(b.w));
}

template <bool WBF16>
__global__ __launch_bounds__(256, 4)
void wavelet_fused(const float* __restrict__ x,
                   const void* __restrict__ w1p,
                   const float* __restrict__ b1,
                   const void* __restrict__ w2p,
                   const float* __restrict__ b2,
                   float* __restrict__ out)
{
  // One buffer, three lives: x_dwt [pix][c4] -> feat [pix][o] -> y [pix][c4].
  __shared__ unsigned short lds[64 * 256];  // exactly 32 KiB (swizzled, no pad)

  const int t  = threadIdx.x;
  const int n  = blockIdx.x >> 6;   // image (b*8+l)
  const int hh = blockIdx.x & 63;   // DWT row

  const int ww = t & 63;            // pixel column (phases 1/4)
  const int cg = t >> 6;

  const int wv   = t >> 6;          // wave id: 64-row o/c4 slice
  const int r    = t & 15;          // MFMA row/col-in-tile
  const int quad = (t & 63) >> 4;   // MFMA quad

  // Per-thread weight bases (row-major [256][256], bf16 or f32)
  const unsigned short* w1b16 = (const unsigned short*)w1p + (wv * 64 + r) * 256 + quad * 8;
  const unsigned short* w2b16 = (const unsigned short*)w2p + (wv * 64 + r) * 256 + quad * 8;
  const float*          w1b32 = (const float*)w1p + (wv * 64 + r) * 256 + quad * 8;
  const float*          w2b32 = (const float*)w2p + (wv * 64 + r) * 256 + quad * 8;

  bf16x8 a_cur[4], a_nxt[4];

  // ---------------- Phase 1: Haar DWT -> lds[ww][q*64+c] (swizzled) ----------------
  {
    const float* xb = x + ((size_t)n * 64 * 128 + (size_t)(2 * hh)) * 128 + 2 * ww;
    float2 r0v[16], r1v[16];
    #pragma unroll
    for (int j = 0; j < 4; ++j)
      #pragma unroll
      for (int ci = 0; ci < 4; ++ci) {
        const float* p = xb + (size_t)((cg + 4 * j) * 4 + ci) * (128 * 128);
        r0v[j * 4 + ci] = *(const float2*)p;          // (2hh,   2ww / 2ww+1)
        r1v[j * 4 + ci] = *(const float2*)(p + 128);  // (2hh+1, ...)
      }
    // Prefetch GEMM1 k0=0 A-fragments; they drain under the DWT + barrier.
    #pragma unroll
    for (int mt = 0; mt < 4; ++mt)
      a_cur[mt] = WBF16 ? *(const bf16x8*)(w1b16 + mt * (16 * 256))
                        : ldw8(w1b32 + mt * (16 * 256));

    #pragma unroll
    for (int j = 0; j < 4; ++j) {
      const int c0 = (cg + 4 * j) * 4;
      float qv[4][4];
      #pragma unroll
      for (int ci = 0; ci < 4; ++ci) {
        const float x1 = r0v[j * 4 + ci].x, x3 = r0v[j * 4 + ci].y;
        const float x2 = r1v[j * 4 + ci].x, x4 = r1v[j * 4 + ci].y;
        qv[0][ci] = 0.5f * ((x1 + x2) + (x3 + x4));
        qv[1][ci] = 0.5f * ((x3 + x4) - (x1 + x2));
        qv[2][ci] = 0.5f * ((x2 + x4) - (x1 + x3));
        qv[3][ci] = 0.5f * ((x1 + x4) - (x2 + x3));
      }
      #pragma unroll
      for (int q = 0; q < 4; ++q) {
        ushort4 v = make_ushort4(f2bf(qv[q][0]), f2bf(qv[q][1]), f2bf(qv[q][2]), f2bf(qv[q][3]));
        *(ushort4*)(&lds[sw(ww, q * 64 + c0)]) = v;
      }
    }
  }
  __syncthreads();

  // ---------------- Phase 2: GEMM1  D[o][pix] = conv_w . x_dwt; silu -> lds[pix][o] ----------------
  {
    f32x4 acc[4][4];
    #pragma unroll
    for (int mt = 0; mt < 4; ++mt)
      #pragma unroll
      for (int nt = 0; nt < 4; ++nt)
        acc[mt][nt] = (f32x4){0.0f, 0.0f, 0.0f, 0.0f};

    #pragma unroll
    for (int k0 = 0; k0 < 256; k0 += 32) {
      // Prefetch next iteration's A frags; the tail prefetches GEMM2's k0=0.
      #pragma unroll
      for (int mt = 0; mt < 4; ++mt) {
        if (k0 < 224)
          a_nxt[mt] = WBF16 ? *(const bf16x8*)(w1b16 + mt * (16 * 256) + k0 + 32)
                            : ldw8(w1b32 + mt * (16 * 256) + k0 + 32);
        else
          a_nxt[mt] = WBF16 ? *(const bf16x8*)(w2b16 + mt * (16 * 256))
                            : ldw8(w2b32 + mt * (16 * 256));
      }
      bf16x8 b[4];
      #pragma unroll
      for (int nt = 0; nt < 4; ++nt)   // B: x_dwt[pix][k] (ds_read_b128, swizzled)
        b[nt] = *(const bf16x8*)(&lds[sw(nt * 16 + r, quad * 8 + k0)]);
      #pragma unroll
      for (int mt = 0; mt < 4; ++mt)
        #pragma unroll
        for (int nt = 0; nt < 4; ++nt)
          acc[mt][nt] = __builtin_amdgcn_mfma_f32_16x16x32_bf16(a_cur[mt], b[nt], acc[mt][nt], 0, 0, 0);
      #pragma unroll
      for (int mt = 0; mt < 4; ++mt)
        a_cur[mt] = a_nxt[mt];
    }
    __syncthreads();  // all GEMM1 reads of lds done

    // Epilogue: lane holds 4 consecutive o (rows) at col pix -> b64 LDS write
    #pragma unroll
    for (int mt = 0; mt < 4; ++mt) {
      const int ob = wv * 64 + mt * 16 + quad * 4;
      const float4 bb = *(const float4*)(b1 + ob);
      #pragma unroll
      for (int nt = 0; nt < 4; ++nt) {
        const int pix = nt * 16 + r;
        ushort4 v;
        v.x = f2bf(silu(acc[mt][nt][0] + bb.x));
        v.y = f2bf(silu(acc[mt][nt][1] + bb.y));
        v.z = f2bf(silu(acc[mt][nt][2] + bb.z));
        v.w = f2bf(silu(acc[mt][nt][3] + bb.w));
        *(ushort4*)(&lds[sw(pix, ob)]) = v;
      }
    }
  }
  __syncthreads();

  // ---------------- Phase 3: GEMM2  D[c4][pix] = conv_out_w . feat -> lds[pix][c4] ----------------
  {
    f32x4 acc[4][4];
    #pragma unroll
    for (int mt = 0; mt < 4; ++mt)
      #pragma unroll
      for (int nt = 0; nt < 4; ++nt)
        acc[mt][nt] = (f32x4){0.0f, 0.0f, 0.0f, 0.0f};

    #pragma unroll
    for (int k0 = 0; k0 < 256; k0 += 32) {
      #pragma unroll
      for (int mt = 0; mt < 4; ++mt)
        if (k0 < 224)
          a_nxt[mt] = WBF16 ? *(const bf16x8*)(w2b16 + mt * (16 * 256) + k0 + 32)
                            : ldw8(w2b32 + mt * (16 * 256) + k0 + 32);
      bf16x8 b[4];
      #pragma unroll
      for (int nt = 0; nt < 4; ++nt)   // B: feat[pix][k] (swizzled)
        b[nt] = *(const bf16x8*)(&lds[sw(nt * 16 + r, quad * 8 + k0)]);
      #pragma unroll
      for (int mt = 0; mt < 4; ++mt)
        #pragma unroll
        for (int nt = 0; nt < 4; ++nt)
          acc[mt][nt] = __builtin_amdgcn_mfma_f32_16x16x32_bf16(a_cur[mt], b[nt], acc[mt][nt], 0, 0, 0);
      if (k0 < 224)
        #pragma unroll
        for (int mt = 0; mt < 4; ++mt)
          a_cur[mt] = a_nxt[mt];
    }
    __syncthreads();  // all GEMM2 reads of lds done

    #pragma unroll
    for (int mt = 0; mt < 4; ++mt) {
      const int cb = wv * 64 + mt * 16 + quad * 4;
      const float4 bb = *(const float4*)(b2 + cb);
      #pragma unroll
      for (int nt = 0; nt < 4; ++nt) {
        const int pix = nt * 16 + r;
        ushort4 v;
        v.x = f2bf(acc[mt][nt][0] + bb.x);
        v.y = f2bf(acc[mt][nt][1] + bb.y);
        v.z = f2bf(acc[mt][nt][2] + bb.z);
        v.w = f2bf(acc[mt][nt][3] + bb.w);
        *(ushort4*)(&lds[sw(pix, cb)]) = v;
      }
    }
  }
  __syncthreads();

  // ---------------- Phase 4: IDWT + coalesced float2 stores ----------------
  {
    float* ob_ = out + ((size_t)n * 64 * 128 + (size_t)(2 * hh)) * 128 + 2 * ww;
    #pragma unroll
    for (int j = 0; j < 4; ++j) {
      const int c0 = (cg + 4 * j) * 4;
      unsigned short yb[4][4];
      #pragma unroll
      for (int q = 0; q < 4; ++q) {
        const ushort4 v = *(const ushort4*)(&lds[sw(ww, q * 64 + c0)]);
        yb[q][0] = v.x; yb[q][1] = v.y; yb[q][2] = v.z; yb[q][3] = v.w;
      }
      #pragma unroll
      for (int ci = 0; ci < 4; ++ci) {
        const float y1 = 0.5f * bf2f(yb[0][ci]);
        const float y2 = 0.5f * bf2f(yb[1][ci]);
        const float y3 = 0.5f * bf2f(yb[2][ci]);
        const float y4 = 0.5f * bf2f(yb[3][ci]);
        const float s14 = y1 + y4, s23 = y2 + y3;
        const float d14 = y1 - y4, d23 = y2 - y3;
        const float oa  = s14 - s23;  // (2hh,   2ww)
        const float oc  = d14 + d23;  // (2hh,   2ww+1)
        const float obv = d14 - d23;  // (2hh+1, 2ww)
        const float od  = s14 + s23;  // (2hh+1, 2ww+1)
        float* prow = ob_ + (size_t)(c0 + ci) * (128 * 128);
        *(float2*)prow         = make_float2(oa, oc);
        *(float2*)(prow + 128) = make_float2(obv, od);
      }
    }
  }
}

extern "C" void kernel_launch(void* const* d_in, const int* in_sizes, int n_in,
                              void* d_out, int out_size, void* d_ws, size_t ws_size,
                              hipStream_t stream) {
  (void)in_sizes; (void)n_in; (void)out_size;
  const float* x  = (const float*)d_in[0];
  const float* w1 = (const float*)d_in[1];
  const float* b1 = (const float*)d_in[2];
  const float* w2 = (const float*)d_in[3];
  const float* b2 = (const float*)d_in[4];
  float* o = (float*)d_out;

  if (ws_size >= 2u * 65536u * sizeof(unsigned short)) {
    unsigned short* wb = (unsigned short*)d_ws;
    cvt_w<<<dim3(64), dim3(256), 0, stream>>>(w1, w2, wb);
    wavelet_fused<true><<<dim3(16 * 64), dim3(256), 0, stream>>>(
        x, wb, b1, wb + 65536, b2, o);
  } else {
    wavelet_fused<false><<<dim3(16 * 64), dim3(256), 0, stream>>>(
        x, w1, b1, w2, b2, o);
  }
}